// Round 3
// baseline (811.975 us; speedup 1.0000x reference)
//
#include <hip/hip_runtime.h>
#include <hip/hip_bf16.h>

// MoE top-2 of 8 experts. T=8192 tokens, D=1024, H=4096.
// route(+cast x) -> scan -> scatter -> transpose w1,w2 -> GEMM1(relu) -> GEMM2(scatter-add)
// GEMMs: 256x256xBK64, 8 waves, 8-phase counted-vmcnt schedule (T3+T4+T5),
// both-sides XOR swizzle (T2), expert-major bijective XCD swizzle (T1).

#define T_TOK   8192
#define DIM     1024
#define NEXP    8
#define HID     4096

typedef unsigned short ushort_t;
typedef __attribute__((ext_vector_type(8))) short bfrag;
typedef __attribute__((ext_vector_type(4))) float f32x4;

#define FENCE() asm volatile("" ::: "memory")

__device__ __forceinline__ ushort_t f2bf(float f) {
    union { float f; unsigned int u; } v; v.f = f;
    unsigned int r = v.u + 0x7FFFu + ((v.u >> 16) & 1u);
    return (ushort_t)(r >> 16);
}

__device__ __forceinline__ void async_load16(const void* g, void* l) {
    __builtin_amdgcn_global_load_lds(
        (const __attribute__((address_space(1))) unsigned int*)g,
        (__attribute__((address_space(3))) unsigned int*)l, 16, 0, 0);
}

// ---------------- routing ----------------
__global__ __launch_bounds__(256)
void route_kern(const float* __restrict__ x, const float* __restrict__ wg,
                ushort_t* __restrict__ x_bf, int* __restrict__ topk,
                float* __restrict__ gates, int* __restrict__ counts)
{
    const int w = threadIdx.x >> 6, lane = threadIdx.x & 63;
    const int t = blockIdx.x * 4 + w;
    const float* xr = x + (size_t)t * DIM;
    float acc[8];
#pragma unroll
    for (int e = 0; e < 8; ++e) acc[e] = 0.f;

#pragma unroll
    for (int it = 0; it < 4; ++it) {
        const int j = it * 256 + lane * 4;
        float4 xv = *(const float4*)(xr + j);
        ushort4 xb;
        xb.x = f2bf(xv.x); xb.y = f2bf(xv.y); xb.z = f2bf(xv.z); xb.w = f2bf(xv.w);
        *(ushort4*)(x_bf + (size_t)t * DIM + j) = xb;
        const float xs[4] = {xv.x, xv.y, xv.z, xv.w};
#pragma unroll
        for (int jj = 0; jj < 4; ++jj) {
            float4 g0 = *(const float4*)(wg + (size_t)(j + jj) * 8);
            float4 g1 = *(const float4*)(wg + (size_t)(j + jj) * 8 + 4);
            acc[0] += xs[jj] * g0.x; acc[1] += xs[jj] * g0.y;
            acc[2] += xs[jj] * g0.z; acc[3] += xs[jj] * g0.w;
            acc[4] += xs[jj] * g1.x; acc[5] += xs[jj] * g1.y;
            acc[6] += xs[jj] * g1.z; acc[7] += xs[jj] * g1.w;
        }
    }
#pragma unroll
    for (int d = 1; d < 64; d <<= 1)
#pragma unroll
        for (int e = 0; e < 8; ++e) acc[e] += __shfl_xor(acc[e], d);

    if (lane == 0) {
        int i0 = 0; float v0 = acc[0];
#pragma unroll
        for (int e = 1; e < 8; ++e) if (acc[e] > v0) { v0 = acc[e]; i0 = e; }
        int i1 = -1; float v1 = -1e30f;
#pragma unroll
        for (int e = 0; e < 8; ++e) if (e != i0 && acc[e] > v1) { v1 = acc[e]; i1 = e; }
        float ex = __expf(v1 - v0);
        float inv = 1.f / (1.f + ex);
        topk[t * 2] = i0; topk[t * 2 + 1] = i1;
        gates[t * 2] = inv; gates[t * 2 + 1] = ex * inv;
        atomicAdd(&counts[i0], 1);
        atomicAdd(&counts[i1], 1);
    }
}

__global__ void scan_kern(const int* __restrict__ counts, int* __restrict__ offs,
                          int* __restrict__ cursors)
{
    if (threadIdx.x == 0) {
        int o = 0;
        for (int e = 0; e < NEXP; ++e) { offs[e] = o; cursors[e] = o; o += counts[e]; }
        offs[NEXP] = o;
    }
}

__global__ __launch_bounds__(256)
void scatter_kern(const int* __restrict__ topk, const float* __restrict__ gates,
                  int* __restrict__ cursors, int* __restrict__ tok_c,
                  float* __restrict__ gate_c)
{
    const int t = blockIdx.x * 256 + threadIdx.x;
#pragma unroll
    for (int k = 0; k < 2; ++k) {
        int e = topk[t * 2 + k];
        int pos = atomicAdd(&cursors[e], 1);
        tok_c[pos] = t;
        gate_c[pos] = gates[t * 2 + k];
    }
}

// ---------------- transpose + cast: [E][K][N] f32 -> [E][N][K] bf16 ----------------
__global__ __launch_bounds__(256)
void transp_kern(const float* __restrict__ in, ushort_t* __restrict__ out, int K, int N)
{
    __shared__ float tile[64][65];
    const int e = blockIdx.z;
    const size_t ibase = (size_t)e * K * N, obase = (size_t)e * N * K;
    const int k0 = blockIdx.y * 64, n0 = blockIdx.x * 64;
    const int tid = threadIdx.x;

    const int r = tid >> 4, c4 = (tid & 15) * 4;
#pragma unroll
    for (int p = 0; p < 4; ++p) {
        int kk = p * 16 + r;
        float4 v = *(const float4*)(in + ibase + (size_t)(k0 + kk) * N + n0 + c4);
        tile[kk][c4] = v.x; tile[kk][c4 + 1] = v.y; tile[kk][c4 + 2] = v.z; tile[kk][c4 + 3] = v.w;
    }
    __syncthreads();
    const int nr = tid >> 6, kc = tid & 63;
#pragma unroll
    for (int p = 0; p < 16; ++p) {
        int nn = p * 4 + nr;
        out[obase + (size_t)(n0 + nn) * K + k0 + kc] = f2bf(tile[kc][nn]);
    }
}

// ---------------- grouped GEMM, 256x256x64, 8 waves, 8-phase counted-vmcnt ----------------
// Buffers alternate per K-tile (kt & 1). Iteration it computes kt0=2it (buf0, phases 1-4,
// m-pair quadrant q=0..3) then kt1=2it+1 (buf1, phases 5-8). Stage schedule (1 half-tile,
// 2 loads/thread per phase) derived so each write targets a region freed >=1 barrier earlier:
//   ph1: A(kt1,h0)->b1   ph2: A(kt1,h1)->b1   ph3: B(kt0+2,h0)->b0  ph4: B(kt0+2,h1)->b0
//   ph5: A(kt0+2,h0)->b0 ph6: A(kt0+2,h1)->b0 ph7: B(kt1+2,h0)->b1  ph8: B(kt1+2,h1)->b1
// vmcnt(4) at ph4 (guarantees A(kt1)+B(kt1) landed) and ph8 (guarantees kt0+2 landed).
template <int STAGE, int NT, int NBLK>
__global__ __launch_bounds__(512, 1)
void gemm256(const ushort_t* __restrict__ A, const ushort_t* __restrict__ Bt,
             ushort_t* __restrict__ Hout, float* __restrict__ Out,
             const int* __restrict__ eoff, const int* __restrict__ tok_c,
             const float* __restrict__ gate_c)
{
    constexpr int K = NT * 64;
    constexpr int N = NBLK * 256;
    constexpr int MB = 32;
    constexpr int NITER = NT / 2;
    __shared__ ushort_t Alds[2][2][128 * 64];   // [ktbuf][half][r'*64+c] 64KB
    __shared__ ushort_t Blds[2][2][128 * 64];   // 64KB

    const int nb = NEXP * MB * NBLK;
    const int orig = blockIdx.x;
    const int lg = (orig & 7) * (nb >> 3) + (orig >> 3);   // nb % 8 == 0: bijective
    const int e = lg / (MB * NBLK);
    const int rem = lg - e * (MB * NBLK);
    const int mblk = rem / NBLK;
    const int nblk = rem - mblk * NBLK;

    const int base = eoff[e];
    const int cnt = eoff[e + 1] - base;
    const int m0 = mblk * 256;
    if (m0 >= cnt) return;
    const int n0 = nblk * 256;

    const int tid = threadIdx.x;
    const int w = tid >> 6, lane = tid & 63;
    const int lhi = lane >> 4, llo = lane & 15;
    const int wm2 = w >> 2;      // wave row half 0..1  (rows wm2*128+)
    const int wn4 = w & 3;       // wave col quarter 0..3 (cols wn4*64+)

    // ---- staging addresses: half-tile = 128 rows x 64 bf16; 2 loads/thread ----
    // ci = w*128 + j*64 + lane ; r' = ci>>3 (= w*16+j*8+(lane>>3)), slot = lane&7
    // source slot pre-swizzled (rule #21): srcslot = slot ^ (r'&7)
    const int rloc = w * 16 + (lane >> 3);
    const int srcslot = (lane & 7) ^ (lane >> 3);
    const ushort_t* Bbase = Bt + (size_t)e * (size_t)N * (size_t)K;
    const ushort_t* aP[2][2];
    const ushort_t* bP[2][2];
#pragma unroll
    for (int h = 0; h < 2; ++h)
#pragma unroll
        for (int j = 0; j < 2; ++j) {
            int r = rloc + j * 8;
            int gr = m0 + h * 128 + r; if (gr >= cnt) gr = cnt - 1;
            size_t arow = (STAGE == 1) ? (size_t)tok_c[base + gr] * (size_t)K
                                       : (size_t)(base + gr) * (size_t)K;
            aP[h][j] = A + arow + srcslot * 8;
            bP[h][j] = Bbase + (size_t)(n0 + h * 128 + r) * K + srcslot * 8;
        }
    const int stoff = w * 2048;   // byte base of this wave's 2KB staging span

    f32x4 acc[8][4];
#pragma unroll
    for (int m = 0; m < 8; ++m)
#pragma unroll
        for (int n = 0; n < 4; ++n) acc[m][n] = (f32x4)(0.f);

    auto stA = [&](int buf, int h, int kt) {
        char* d = (char*)(&Alds[buf][h][0]) + stoff;
        async_load16(aP[h][0] + kt * 64, d);
        async_load16(aP[h][1] + kt * 64, d + 1024);
    };
    auto stB = [&](int buf, int h, int kt) {
        char* d = (char*)(&Blds[buf][h][0]) + stoff;
        async_load16(bP[h][0] + kt * 64, d);
        async_load16(bP[h][1] + kt * 64, d + 1024);
    };

    bfrag af[2][2], bf[4][2];
    auto ldA = [&](int buf, int q) {
        const char* p = (const char*)(&Alds[buf][wm2][0]);
#pragma unroll
        for (int mi = 0; mi < 2; ++mi) {
            int r = (q * 2 + mi) * 16 + llo;
#pragma unroll
            for (int ks = 0; ks < 2; ++ks) {
                int kb = ks * 64 + lhi * 16;
                af[mi][ks] = *(const bfrag*)(p + r * 128 + (kb ^ ((r & 7) << 4)));
            }
        }
    };
    auto ldB = [&](int buf) {
        const char* p = (const char*)(&Blds[buf][wn4 >> 1][0]);
#pragma unroll
        for (int n = 0; n < 4; ++n) {
            int r = (wn4 & 1) * 64 + n * 16 + llo;
#pragma unroll
            for (int ks = 0; ks < 2; ++ks) {
                int kb = ks * 64 + lhi * 16;
                bf[n][ks] = *(const bfrag*)(p + r * 128 + (kb ^ ((r & 7) << 4)));
            }
        }
    };

#define PH(q, rb, LOADB, STAGE_STMT, VMW)                          \
    {                                                              \
        if (LOADB) ldB(rb);                                        \
        ldA(rb, q);                                                \
        STAGE_STMT;                                                \
        FENCE(); __builtin_amdgcn_s_barrier(); FENCE();            \
        asm volatile("s_waitcnt lgkmcnt(0)" ::: "memory");         \
        __builtin_amdgcn_sched_barrier(0);                         \
        __builtin_amdgcn_s_setprio(1);                             \
        _Pragma("unroll")                                          \
        for (int mi = 0; mi < 2; ++mi)                             \
            _Pragma("unroll")                                      \
            for (int n = 0; n < 4; ++n)                            \
                _Pragma("unroll")                                  \
                for (int ks = 0; ks < 2; ++ks)                     \
                    acc[(q) * 2 + mi][n] = __builtin_amdgcn_mfma_f32_16x16x32_bf16( \
                        af[mi][ks], bf[n][ks], acc[(q) * 2 + mi][n], 0, 0, 0);      \
        __builtin_amdgcn_s_setprio(0);                             \
        VMW;                                                       \
        FENCE(); __builtin_amdgcn_s_barrier(); FENCE();            \
    }

    // prologue: buf0 <- kt0=0 (A,B), buf1 <- B(kt=1); A(kt=1) staged in ph1-2.
    stA(0, 0, 0); stA(0, 1, 0); stB(0, 0, 0); stB(0, 1, 0);
    stB(1, 0, 1); stB(1, 1, 1);
    asm volatile("s_waitcnt vmcnt(0)" ::: "memory");
    FENCE(); __builtin_amdgcn_s_barrier(); FENCE();

    for (int it = 0; it < NITER; ++it) {
        const int kt0 = 2 * it, kt1 = 2 * it + 1;
        const bool nx = (it + 1 < NITER);
        // group 1: buf0 / kt0
        PH(0, 0, true,  stA(1, 0, kt1), );
        PH(1, 0, false, stA(1, 1, kt1), );
        PH(2, 0, false, if (nx) stB(0, 0, kt0 + 2), );
        PH(3, 0, false, if (nx) stB(0, 1, kt0 + 2),
           if (nx) { asm volatile("s_waitcnt vmcnt(4)" ::: "memory"); }
           else    { asm volatile("s_waitcnt vmcnt(0)" ::: "memory"); } );
        // group 2: buf1 / kt1
        PH(0, 1, true,  if (nx) stA(0, 0, kt0 + 2), );
        PH(1, 1, false, if (nx) stA(0, 1, kt0 + 2), );
        PH(2, 1, false, if (nx) stB(1, 0, kt1 + 2), );
        PH(3, 1, false, if (nx) stB(1, 1, kt1 + 2),
           asm volatile("s_waitcnt vmcnt(4)" ::: "memory"); );
    }
#undef PH

    if (STAGE == 1) {
#pragma unroll
        for (int m = 0; m < 8; ++m)
#pragma unroll
            for (int i = 0; i < 4; ++i) {
                int row = wm2 * 128 + (m << 4) + (lhi << 2) + i;
                int gr = m0 + row;
                if (gr >= cnt) continue;
                size_t rb = (size_t)(base + gr) * (size_t)N + n0 + wn4 * 64;
#pragma unroll
                for (int n = 0; n < 4; ++n) {
                    float v = acc[m][n][i];
                    Hout[rb + (n << 4) + llo] = f2bf(v > 0.f ? v : 0.f);
                }
            }
    } else {
#pragma unroll
        for (int m = 0; m < 8; ++m)
#pragma unroll
            for (int i = 0; i < 4; ++i) {
                int row = wm2 * 128 + (m << 4) + (lhi << 2) + i;
                int gr = m0 + row;
                if (gr >= cnt) continue;
                int tok = tok_c[base + gr];
                float g = gate_c[base + gr];
                size_t rb = (size_t)tok * (size_t)N + n0 + wn4 * 64;
#pragma unroll
                for (int n = 0; n < 4; ++n)
                    atomicAdd(&Out[rb + (n << 4) + llo], g * acc[m][n][i]);
            }
    }
}

extern "C" void kernel_launch(void* const* d_in, const int* in_sizes, int n_in,
                              void* d_out, int out_size, void* d_ws, size_t ws_size,
                              hipStream_t stream)
{
    const float* x  = (const float*)d_in[0];   // [4,2048,1024]
    const float* wg = (const float*)d_in[1];   // [1024,8]
    const float* w1 = (const float*)d_in[2];   // [8,1024,4096]
    const float* w2 = (const float*)d_in[3];   // [8,4096,1024]
    float* out = (float*)d_out;                // [4,2048,1024] f32

    char* ws = (char*)d_ws;
    ushort_t* x_bf = (ushort_t*)(ws + 0);              // 16,777,216
    ushort_t* w1t  = (ushort_t*)(ws + 16777216);       // 67,108,864  [E][4096][1024]
    ushort_t* w2t  = (ushort_t*)(ws + 83886080);       // 67,108,864  [E][1024][4096]
    ushort_t* h    = (ushort_t*)(ws + 150994944);      // 134,217,728 [16384][4096]
    char* ctrl     = ws + 285212672;
    int*   topk    = (int*)(ctrl);
    float* gates   = (float*)(ctrl + 65536);
    int*   tok_c   = (int*)(ctrl + 131072);
    float* gate_c  = (float*)(ctrl + 196608);
    int*   counts  = (int*)(ctrl + 262144);
    int*   offs    = (int*)(ctrl + 262144 + 64);
    int*   cursors = (int*)(ctrl + 262144 + 128);

    hipMemsetAsync(counts, 0, NEXP * sizeof(int), stream);
    hipMemsetAsync(out, 0, (size_t)T_TOK * DIM * sizeof(float), stream);

    route_kern<<<T_TOK / 4, 256, 0, stream>>>(x, wg, x_bf, topk, gates, counts);
    transp_kern<<<dim3(HID / 64, DIM / 64, NEXP), 256, 0, stream>>>(w1, w1t, DIM, HID);
    transp_kern<<<dim3(DIM / 64, HID / 64, NEXP), 256, 0, stream>>>(w2, w2t, HID, DIM);
    scan_kern<<<1, 64, 0, stream>>>(counts, offs, cursors);
    scatter_kern<<<T_TOK / 256, 256, 0, stream>>>(topk, gates, cursors, tok_c, gate_c);

    // GEMM1: h = relu(x_bf[tok] @ w1t^T), K=1024 (NT=16), N=4096 (NBLK=16)
    gemm256<1, 16, 16><<<NEXP * 32 * 16, 512, 0, stream>>>(
        x_bf, w1t, h, nullptr, offs, tok_c, gate_c);
    // GEMM2: out[tok] += gate * (h @ w2t^T), K=4096 (NT=64), N=1024 (NBLK=4)
    gemm256<2, 64, 4><<<NEXP * 32 * 4, 512, 0, stream>>>(
        h, w2t, nullptr, out, offs, tok_c, gate_c);
}